// Round 3
// baseline (84.627 us; speedup 1.0000x reference)
//
#include <hip/hip_runtime.h>

// Problem: A=1, B=32, M=32, H=1024, E=8, N=1024 (all fp32)
// out[b,e] = mask[b,e] * sum_h (sum_m hidden[b,m,h]) * (sum_n weight[e,h,n])
//
// ws layout (float4 units): [0, 2048)            wsum   (E*H floats)
//                           [2048, 2048+131072)  hidden partials:
//                               16 m-split partials x 8192 float4 outputs
//                               partial p covers m in {2p, 2p+1}

#define Bdim 32
#define Mdim 32
#define Hdim 1024
#define Edim 8
#define Ndim 1024
#define EH4  2048   // E*H/4 in float4 units

// Kernel A: 512 blocks x 256 threads, exactly 2 blocks/CU, uniform work.
// Per thread: one hidden m-split partial (2 coalesced float4 loads + 1 store).
// Per wave:   4 weight rows of N=1024, float4 loads + shuffle reduce.
__global__ __launch_bounds__(256) void reduce_kernel(
    const float* __restrict__ hidden,   // (B,M,H)
    const float* __restrict__ weight,   // (E,H,N)
    float* __restrict__ ws)
{
    const int tid = threadIdx.x;

    // ---- hidden partial: task g in [0, 131072) = p*8192 + (b*256 + col) ----
    {
        const int g   = blockIdx.x * 256 + tid;
        const int p   = g >> 13;          // 0..15  -> m in {2p, 2p+1}
        const int idx = g & 8191;         // b*256 + col
        const int b   = idx >> 8;
        const int col = idx & 255;
        const float4* h4 = reinterpret_cast<const float4*>(hidden);
        const float4* v0p = h4 + b * (Mdim * Hdim / 4) + (2 * p) * (Hdim / 4) + col;
        float4 v0 = v0p[0];
        float4 v1 = v0p[Hdim / 4];
        float4 s4 = {v0.x + v1.x, v0.y + v1.y, v0.z + v1.z, v0.w + v1.w};
        reinterpret_cast<float4*>(ws)[EH4 + g] = s4;
    }

    // ---- weight rows: wave per 4 rows, 8192 rows total ----
    const int wave = blockIdx.x * 4 + (tid >> 6);
    const int lane = tid & 63;
    const float4* w4 = reinterpret_cast<const float4*>(weight);
    #pragma unroll
    for (int r = 0; r < 4; ++r) {
        const int row = wave * 4 + r;          // row = e*H + h, 0..8191
        float s = 0.f;
        #pragma unroll
        for (int j = 0; j < 4; ++j) {
            float4 v = w4[row * (Ndim / 4) + j * 64 + lane];
            s += (v.x + v.y) + (v.z + v.w);
        }
        #pragma unroll
        for (int off = 32; off > 0; off >>= 1)
            s += __shfl_xor(s, off, 64);
        if (lane == 0) ws[row] = s;
    }
}

// Kernel B: 256 waves, one per (b,e); sums the 16 hidden partials and dots
// with wsum[e,:], masked by sparsity[b,e]. All reads L2-hot (~300 KB).
__global__ __launch_bounds__(256) void dot_kernel(
    const float* __restrict__ ws,
    const float* __restrict__ sparsity,  // (B,E) flat
    float* __restrict__ out)             // (B,E) flat
{
    const int o    = blockIdx.x * 4 + (threadIdx.x >> 6);   // b*E + e
    const int lane = threadIdx.x & 63;
    const int b = o >> 3;
    const int e = o & 7;
    const float4* ws4 = reinterpret_cast<const float4*>(ws);
    float s = 0.f;
    #pragma unroll
    for (int j = 0; j < 4; ++j) {
        const int h4  = j * 64 + lane;
        const int idx = b * 256 + h4;
        float4 acc = ws4[EH4 + idx];              // partial p=0
        #pragma unroll
        for (int p = 1; p < 16; ++p) {
            float4 v = ws4[EH4 + p * 8192 + idx];
            acc.x += v.x; acc.y += v.y; acc.z += v.z; acc.w += v.w;
        }
        float4 w = ws4[e * 256 + h4];
        s += acc.x * w.x + acc.y * w.y + acc.z * w.z + acc.w * w.w;
    }
    #pragma unroll
    for (int off = 32; off > 0; off >>= 1)
        s += __shfl_xor(s, off, 64);
    if (lane == 0) out[o] = s * sparsity[o];
}

extern "C" void kernel_launch(void* const* d_in, const int* in_sizes, int n_in,
                              void* d_out, int out_size, void* d_ws, size_t ws_size,
                              hipStream_t stream) {
    const float* hidden   = (const float*)d_in[0];  // (1,32,32,1024)
    const float* sparsity = (const float*)d_in[1];  // (1,32,1,8)
    const float* weight   = (const float*)d_in[2];  // (1,8,1024,1024)
    float* out = (float*)d_out;                     // (1,32,8)
    float* ws  = (float*)d_ws;

    reduce_kernel<<<512, 256, 0, stream>>>(hidden, weight, ws);
    dot_kernel<<<64, 256, 0, stream>>>(ws, sparsity, out);
}